// Round 13
// baseline (287.243 us; speedup 1.0000x reference)
//
#include <hip/hip_runtime.h>
#include <hip/hip_bf16.h>

typedef unsigned int u32;
typedef unsigned short u16;
typedef short bf16x8 __attribute__((ext_vector_type(8)));
typedef float f32x4 __attribute__((ext_vector_type(4)));

static __device__ __forceinline__ float bf_lo(u32 v) { return __uint_as_float(v << 16); }
static __device__ __forceinline__ float bf_hi(u32 v) { return __uint_as_float(v & 0xffff0000u); }
static __device__ __forceinline__ u16 f2bf(float f) {
    u32 u = __float_as_uint(f);
    u32 r = u + 0x7fffu + ((u >> 16) & 1u);   // RNE; inputs finite
    return (u16)(r >> 16);
}
static __device__ __forceinline__ u32 pack2(float a, float b) {
    return ((u32)f2bf(b) << 16) | (u32)f2bf(a);
}

// ---------------------------------------------------------------------------
// merged prep: blocks [0,2048) convert f32->bf16; [2048,2304) bhist;
// [2304,2560) wprep
// ---------------------------------------------------------------------------
__global__ __launch_bounds__(256) void prep_k(const float* __restrict__ x,
                                              u32* __restrict__ out2, int total4,
                                              const int* __restrict__ edst,
                                              int* __restrict__ gcount, int E, int NB,
                                              const float* __restrict__ Wa,
                                              const float* __restrict__ Wb,
                                              const float* __restrict__ Wc,
                                              const float* __restrict__ Wd,
                                              u16* __restrict__ Wf)
{
    int b = blockIdx.x, t = threadIdx.x;
    if (b < 2048) {                       // ---- convert role ----
        for (int i = b * 256 + t; i < total4; i += 2048 * 256) {
            float4 v = reinterpret_cast<const float4*>(x)[i];
            out2[2 * i + 0] = pack2(v.x, v.y);
            out2[2 * i + 1] = pack2(v.z, v.w);
        }
    } else if (b < 2304) {                // ---- bhist role ----
        __shared__ int lh[1024];
        for (int i = t; i < 1024; i += 256) lh[i] = 0;
        __syncthreads();
        for (int e = (b - 2048) * 256 + t; e < E; e += 256 * 256)
            atomicAdd(&lh[edst[e] >> 7], 1);
        __syncthreads();
        for (int bb = t; bb < NB; bb += 256)
            if (lh[bb]) atomicAdd(&gcount[bb], lh[bb]);
    } else {                              // ---- wprep role ----
        int g = (b - 2304) * 256 + t;     // 0..65535
        int which = g >> 14;
        int tt = g & 16383;
        const float* W = which == 0 ? Wa : which == 1 ? Wb : which == 2 ? Wc : Wd;
        int j  = tt & 7;
        int l  = (tt >> 3) & 63;
        int nb = (tt >> 9) & 7;
        int kg = (tt >> 12) & 3;
        int k  = kg * 32 + (l >> 4) * 8 + j;
        int n  = nb * 16 + (l & 15);
        Wf[g] = f2bf(W[k * 128 + n]);
    }
}

// generic 1-block exclusive scan over <=1024 entries (also emits total at [n])
__global__ __launch_bounds__(1024) void bscan_k(const int* __restrict__ cnt,
                                                int* __restrict__ outoffs,
                                                int* __restrict__ outcur, int n)
{
    __shared__ int s[1024];
    int t = threadIdx.x;
    int v = (t < n) ? cnt[t] : 0;
    s[t] = v; __syncthreads();
    for (int d = 1; d < 1024; d <<= 1) {
        int x = (t >= d) ? s[t - d] : 0;
        __syncthreads();
        s[t] += x;
        __syncthreads();
    }
    if (t < n) { int o = s[t] - v; outoffs[t] = o; if (outcur) outcur[t] = o; }
    if (t == n - 1) outoffs[n] = s[t];
}

__global__ __launch_bounds__(256) void bfill_k(const int* __restrict__ esrc,
                                               const int* __restrict__ edst,
                                               int* __restrict__ gcur,
                                               u32* __restrict__ bpacked, int E, int NB)
{
    __shared__ int lh[1024];
    __shared__ int lbase[1024];
    int t = threadIdx.x;
    for (int i = t; i < 1024; i += 256) lh[i] = 0;
    __syncthreads();
    int per = (E + gridDim.x - 1) / gridDim.x;
    int lo = blockIdx.x * per;
    int hi = lo + per; if (hi > E) hi = E;
    for (int e = lo + t; e < hi; e += 256) atomicAdd(&lh[edst[e] >> 7], 1);
    __syncthreads();
    for (int b = t; b < NB; b += 256) {
        int c = lh[b];
        lbase[b] = c ? atomicAdd(&gcur[b], c) : 0;
    }
    __syncthreads();
    for (int i = t; i < 1024; i += 256) lh[i] = 0;   // reuse as local cursor
    __syncthreads();
    for (int e = lo + t; e < hi; e += 256) {
        int d = edst[e];
        int b = d >> 7;
        int idx = atomicAdd(&lh[b], 1);
        bpacked[lbase[b] + idx] = ((u32)(d & 127) << 17) | (u32)esrc[e];
    }
}

// ---------------------------------------------------------------------------
// fsortA: per bucket histogram -> deg[] + padded bucket total (pad16)
// ---------------------------------------------------------------------------
__global__ __launch_bounds__(256) void fsortA_k(const u32* __restrict__ bpacked,
                                                const int* __restrict__ goffs,
                                                int* __restrict__ deg,
                                                int* __restrict__ pbtotal, int N)
{
    __shared__ int cnt[128];
    __shared__ int red[256];
    int b = blockIdx.x, t = threadIdx.x;
    int start = goffs[b], end = goffs[b + 1];
    if (t < 128) cnt[t] = 0;
    __syncthreads();
    for (int e = start + t; e < end; e += 256)
        atomicAdd(&cnt[bpacked[e] >> 17], 1);
    __syncthreads();
    int row0 = b * 128;
    if (t < 128 && row0 + t < N) deg[row0 + t] = cnt[t];
    red[t] = (t < 128) ? ((cnt[t] + 15) & ~15) : 0;
    __syncthreads();
    for (int d = 128; d >= 1; d >>= 1) {
        if (t < d) red[t] += red[t + d];
        __syncthreads();
    }
    if (t == 0) pbtotal[b] = red[0];
}

// ---------------------------------------------------------------------------
// fsortB: place edges into PADDED slots (offs = padded base), fill pads with
// zero-row sentinels N+(i&15)
// ---------------------------------------------------------------------------
__global__ __launch_bounds__(256) void fsortB_k(const u32* __restrict__ bpacked,
                                                const int* __restrict__ goffs,
                                                const int* __restrict__ pbase,
                                                const int* __restrict__ deg,
                                                int* __restrict__ slots,
                                                int* __restrict__ offs, int N)
{
    __shared__ int cnt[128];
    __shared__ int roff[128];
    __shared__ int sb[128];
    int b = blockIdx.x, t = threadIdx.x;
    int start = goffs[b], end = goffs[b + 1];
    int row0 = b * 128;
    int myc = (t < 128 && row0 + t < N) ? deg[row0 + t] : 0;
    int pd = (myc + 15) & ~15;
    if (t < 128) { sb[t] = pd; cnt[t] = 0; }
    __syncthreads();
    for (int d = 1; d < 128; d <<= 1) {
        int x = (t < 128 && t >= d) ? sb[t - d] : 0;
        __syncthreads();
        if (t < 128) sb[t] += x;
        __syncthreads();
    }
    int base = pbase[b];
    if (t < 128) {
        roff[t] = sb[t] - pd;   // padded exclusive prefix within bucket
        if (row0 + t < N) offs[row0 + t] = base + roff[t];
    }
    __syncthreads();
    for (int e = start + t; e < end; e += 256) {
        u32 pk = bpacked[e];
        int local = (int)(pk >> 17);
        int idx = atomicAdd(&cnt[local], 1);
        slots[base + roff[local] + idx] = (int)(pk & 0x1FFFF);
    }
    __syncthreads();
    if (t < 128) {
        int o = base + roff[t];
        for (int i = myc; i < pd; ++i) slots[o + i] = N + (i & 15);
    }
}

// ---------------------------------------------------------------------------
// gather-aggregate: one wave per row, scalar-hoisted CSR, sentinel-padded
// slots (pad16): loop is fully unconditional -> ONE memory round trip for
// 99.97% of rows (32-batch for pdg==32, 16-batch for pdg==16).
// MODE 0: xa[row] = bf16( x[row] + sum_nbr x[s] )
// MODE 1: prev-layer BN folded in: xa[row] = bf16( sc.(h+sum) + (deg+1).sh )
// ---------------------------------------------------------------------------
#define ROWP(s) reinterpret_cast<const u32*>(xbase + ((size_t)(u32)(s) << 8))

template<int MODE>
__global__ __launch_bounds__(256) void gather_k(const u32* __restrict__ xb2,
                                                const int* __restrict__ offs,
                                                const int* __restrict__ deg,
                                                const int* __restrict__ slots,
                                                const float* __restrict__ stats_in,
                                                const float* __restrict__ g_in,
                                                const float* __restrict__ be_in,
                                                u32* __restrict__ xa2, int N)
{
    __shared__ float sc[128], sh[128];
    int t = threadIdx.x;
    if (MODE == 1) {
        if (t < 128) {
            float invN = 1.0f / (float)N;
            float mean = stats_in[t] * invN;
            float var  = stats_in[128 + t] * invN - mean * mean;
            float s = g_in[t] * rsqrtf(var + 1e-5f);
            sc[t] = s;
            sh[t] = be_in[t] - mean * s;
        }
        __syncthreads();
    }

    int row = blockIdx.x * 4 + (t >> 6);
    if (row >= N) return;
    int lane = t & 63;
    const char* xbase = (const char*)xb2;

    u32 self = ROWP(row)[lane];
    float ax0 = bf_lo(self), ay0 = bf_hi(self);
    float ax1 = 0.f, ay1 = 0.f, ax2 = 0.f, ay2 = 0.f, ax3 = 0.f, ay3 = 0.f;

    int ustart = __builtin_amdgcn_readfirstlane(offs[row]);
    int udg    = __builtin_amdgcn_readfirstlane(deg[row]);
    int pdg    = (udg + 15) & ~15;

    int e = 0;
    for (; e + 32 <= pdg; e += 32) {   // 32 loads in flight, unconditional
        int s0 = slots[ustart + e + 0],  s1 = slots[ustart + e + 1];
        int s2 = slots[ustart + e + 2],  s3 = slots[ustart + e + 3];
        int s4 = slots[ustart + e + 4],  s5 = slots[ustart + e + 5];
        int s6 = slots[ustart + e + 6],  s7 = slots[ustart + e + 7];
        int s8 = slots[ustart + e + 8],  s9 = slots[ustart + e + 9];
        int sA = slots[ustart + e + 10], sB = slots[ustart + e + 11];
        int sC = slots[ustart + e + 12], sD = slots[ustart + e + 13];
        int sE = slots[ustart + e + 14], sF = slots[ustart + e + 15];
        int sG = slots[ustart + e + 16], sH = slots[ustart + e + 17];
        int sI = slots[ustart + e + 18], sJ = slots[ustart + e + 19];
        int sK = slots[ustart + e + 20], sL = slots[ustart + e + 21];
        int sM = slots[ustart + e + 22], sN_ = slots[ustart + e + 23];
        int sO = slots[ustart + e + 24], sP = slots[ustart + e + 25];
        int sQ = slots[ustart + e + 26], sR = slots[ustart + e + 27];
        int sS = slots[ustart + e + 28], sT = slots[ustart + e + 29];
        int sU = slots[ustart + e + 30], sV = slots[ustart + e + 31];
        u32 v0 = ROWP(s0)[lane], v1 = ROWP(s1)[lane];
        u32 v2 = ROWP(s2)[lane], v3 = ROWP(s3)[lane];
        u32 v4 = ROWP(s4)[lane], v5 = ROWP(s5)[lane];
        u32 v6 = ROWP(s6)[lane], v7 = ROWP(s7)[lane];
        u32 v8 = ROWP(s8)[lane], v9 = ROWP(s9)[lane];
        u32 vA = ROWP(sA)[lane], vB = ROWP(sB)[lane];
        u32 vC = ROWP(sC)[lane], vD = ROWP(sD)[lane];
        u32 vE = ROWP(sE)[lane], vF = ROWP(sF)[lane];
        u32 vG = ROWP(sG)[lane], vH = ROWP(sH)[lane];
        u32 vI = ROWP(sI)[lane], vJ = ROWP(sJ)[lane];
        u32 vK = ROWP(sK)[lane], vL = ROWP(sL)[lane];
        u32 vM = ROWP(sM)[lane], vN = ROWP(sN_)[lane];
        u32 vO = ROWP(sO)[lane], vP = ROWP(sP)[lane];
        u32 vQ = ROWP(sQ)[lane], vR = ROWP(sR)[lane];
        u32 vS = ROWP(sS)[lane], vT = ROWP(sT)[lane];
        u32 vU = ROWP(sU)[lane], vV = ROWP(sV)[lane];
        ax0 += bf_lo(v0); ay0 += bf_hi(v0);  ax1 += bf_lo(v1); ay1 += bf_hi(v1);
        ax2 += bf_lo(v2); ay2 += bf_hi(v2);  ax3 += bf_lo(v3); ay3 += bf_hi(v3);
        ax0 += bf_lo(v4); ay0 += bf_hi(v4);  ax1 += bf_lo(v5); ay1 += bf_hi(v5);
        ax2 += bf_lo(v6); ay2 += bf_hi(v6);  ax3 += bf_lo(v7); ay3 += bf_hi(v7);
        ax0 += bf_lo(v8); ay0 += bf_hi(v8);  ax1 += bf_lo(v9); ay1 += bf_hi(v9);
        ax2 += bf_lo(vA); ay2 += bf_hi(vA);  ax3 += bf_lo(vB); ay3 += bf_hi(vB);
        ax0 += bf_lo(vC); ay0 += bf_hi(vC);  ax1 += bf_lo(vD); ay1 += bf_hi(vD);
        ax2 += bf_lo(vE); ay2 += bf_hi(vE);  ax3 += bf_lo(vF); ay3 += bf_hi(vF);
        ax0 += bf_lo(vG); ay0 += bf_hi(vG);  ax1 += bf_lo(vH); ay1 += bf_hi(vH);
        ax2 += bf_lo(vI); ay2 += bf_hi(vI);  ax3 += bf_lo(vJ); ay3 += bf_hi(vJ);
        ax0 += bf_lo(vK); ay0 += bf_hi(vK);  ax1 += bf_lo(vL); ay1 += bf_hi(vL);
        ax2 += bf_lo(vM); ay2 += bf_hi(vM);  ax3 += bf_lo(vN); ay3 += bf_hi(vN);
        ax0 += bf_lo(vO); ay0 += bf_hi(vO);  ax1 += bf_lo(vP); ay1 += bf_hi(vP);
        ax2 += bf_lo(vQ); ay2 += bf_hi(vQ);  ax3 += bf_lo(vR); ay3 += bf_hi(vR);
        ax0 += bf_lo(vS); ay0 += bf_hi(vS);  ax1 += bf_lo(vT); ay1 += bf_hi(vT);
        ax2 += bf_lo(vU); ay2 += bf_hi(vU);  ax3 += bf_lo(vV); ay3 += bf_hi(vV);
    }
    if (e < pdg) {                     // exactly one 16-batch, unconditional
        int s0 = slots[ustart + e + 0],  s1 = slots[ustart + e + 1];
        int s2 = slots[ustart + e + 2],  s3 = slots[ustart + e + 3];
        int s4 = slots[ustart + e + 4],  s5 = slots[ustart + e + 5];
        int s6 = slots[ustart + e + 6],  s7 = slots[ustart + e + 7];
        int s8 = slots[ustart + e + 8],  s9 = slots[ustart + e + 9];
        int sA = slots[ustart + e + 10], sB = slots[ustart + e + 11];
        int sC = slots[ustart + e + 12], sD = slots[ustart + e + 13];
        int sE = slots[ustart + e + 14], sF = slots[ustart + e + 15];
        u32 v0 = ROWP(s0)[lane], v1 = ROWP(s1)[lane];
        u32 v2 = ROWP(s2)[lane], v3 = ROWP(s3)[lane];
        u32 v4 = ROWP(s4)[lane], v5 = ROWP(s5)[lane];
        u32 v6 = ROWP(s6)[lane], v7 = ROWP(s7)[lane];
        u32 v8 = ROWP(s8)[lane], v9 = ROWP(s9)[lane];
        u32 vA = ROWP(sA)[lane], vB = ROWP(sB)[lane];
        u32 vC = ROWP(sC)[lane], vD = ROWP(sD)[lane];
        u32 vE = ROWP(sE)[lane], vF = ROWP(sF)[lane];
        ax0 += bf_lo(v0); ay0 += bf_hi(v0);  ax1 += bf_lo(v1); ay1 += bf_hi(v1);
        ax2 += bf_lo(v2); ay2 += bf_hi(v2);  ax3 += bf_lo(v3); ay3 += bf_hi(v3);
        ax0 += bf_lo(v4); ay0 += bf_hi(v4);  ax1 += bf_lo(v5); ay1 += bf_hi(v5);
        ax2 += bf_lo(v6); ay2 += bf_hi(v6);  ax3 += bf_lo(v7); ay3 += bf_hi(v7);
        ax0 += bf_lo(v8); ay0 += bf_hi(v8);  ax1 += bf_lo(v9); ay1 += bf_hi(v9);
        ax2 += bf_lo(vA); ay2 += bf_hi(vA);  ax3 += bf_lo(vB); ay3 += bf_hi(vB);
        ax0 += bf_lo(vC); ay0 += bf_hi(vC);  ax1 += bf_lo(vD); ay1 += bf_hi(vD);
        ax2 += bf_lo(vE); ay2 += bf_hi(vE);  ax3 += bf_lo(vF); ay3 += bf_hi(vF);
    }

    float ax = (ax0 + ax1) + (ax2 + ax3);
    float ay = (ay0 + ay1) + (ay2 + ay3);
    if (MODE == 1) {
        float d1 = (float)(udg + 1);
        ax = sc[2 * lane]     * ax + d1 * sh[2 * lane];
        ay = sc[2 * lane + 1] * ay + d1 * sh[2 * lane + 1];
    }
    xa2[(size_t)row * 64 + lane] = pack2(ax, ay);
}

// ---------------------------------------------------------------------------
// fused MFMA MLP (round-12 version, unchanged)
// ---------------------------------------------------------------------------
__global__ __launch_bounds__(256) void mlp_mfma_k(
    const u16* __restrict__ xa,
    const u16* __restrict__ wfa, const float* __restrict__ ba,
    const u16* __restrict__ wfb, const float* __restrict__ bb,
    u16* __restrict__ hb_out, float* __restrict__ partial, int N)
{
    __shared__ short ta[64 * 128];
    __shared__ float ssum[256];

    int t = threadIdx.x;
    int w = t >> 6, l = t & 63;
    int row0 = blockIdx.x * 64;

    for (int c = t; c < 1024; c += 256) {
        int r = c >> 4, ci = c & 15;
        int dst = (r * 128 + ci * 8) ^ ((r & 7) << 3);
        f32x4 v;
        if (row0 + r < N)
            v = *reinterpret_cast<const f32x4*>(xa + ((size_t)(row0 + r) * 128 + ci * 8));
        else
            v = f32x4{0.f, 0.f, 0.f, 0.f};
        *reinterpret_cast<f32x4*>(ta + dst) = v;
    }

    bf16x8 wf[2][4];
#pragma unroll
    for (int nr = 0; nr < 2; ++nr) {
        int nb = 2 * w + nr;
#pragma unroll
        for (int kg = 0; kg < 4; ++kg)
            wf[nr][kg] = *reinterpret_cast<const bf16x8*>(
                wfa + ((size_t)((kg * 8 + nb) * 64 + l)) * 8);
    }
    __syncthreads();

    int rr = l & 15;
    int kg8 = l >> 4;

    f32x4 acc[4][2];
#pragma unroll
    for (int mr = 0; mr < 4; ++mr)
#pragma unroll
        for (int nr = 0; nr < 2; ++nr)
            acc[mr][nr] = f32x4{0.f, 0.f, 0.f, 0.f};

#pragma unroll
    for (int mr = 0; mr < 4; ++mr) {
        int r = mr * 16 + rr;
        bf16x8 af[4];
#pragma unroll
        for (int kg = 0; kg < 4; ++kg) {
            int idx = (r * 128 + kg * 32 + kg8 * 8) ^ ((r & 7) << 3);
            af[kg] = *reinterpret_cast<const bf16x8*>(ta + idx);
        }
#pragma unroll
        for (int nr = 0; nr < 2; ++nr)
#pragma unroll
            for (int kg = 0; kg < 4; ++kg)
                acc[mr][nr] = __builtin_amdgcn_mfma_f32_16x16x32_bf16(
                    af[kg], wf[nr][kg], acc[mr][nr], 0, 0, 0);
    }
    __syncthreads();

    bf16x8 wf2[2][4];
#pragma unroll
    for (int nr = 0; nr < 2; ++nr) {
        int nb = 2 * w + nr;
#pragma unroll
        for (int kg = 0; kg < 4; ++kg)
            wf2[nr][kg] = *reinterpret_cast<const bf16x8*>(
                wfb + ((size_t)((kg * 8 + nb) * 64 + l)) * 8);
    }

    int colb = w * 32;
    float b0 = ba[colb + rr];
    float b1 = ba[colb + 16 + rr];
#pragma unroll
    for (int mr = 0; mr < 4; ++mr)
#pragma unroll
        for (int nr = 0; nr < 2; ++nr) {
            float bb_ = nr ? b1 : b0;
            int col = colb + nr * 16 + rr;
#pragma unroll
            for (int reg = 0; reg < 4; ++reg) {
                int row = mr * 16 + kg8 * 4 + reg;
                float v = fmaxf(acc[mr][nr][reg] + bb_, 0.0f);
                ta[(row * 128 + col) ^ ((row & 7) << 3)] = (short)f2bf(v);
            }
        }
    __syncthreads();

#pragma unroll
    for (int mr = 0; mr < 4; ++mr)
#pragma unroll
        for (int nr = 0; nr < 2; ++nr)
            acc[mr][nr] = f32x4{0.f, 0.f, 0.f, 0.f};

#pragma unroll
    for (int mr = 0; mr < 4; ++mr) {
        int r = mr * 16 + rr;
        bf16x8 af[4];
#pragma unroll
        for (int kg = 0; kg < 4; ++kg) {
            int idx = (r * 128 + kg * 32 + kg8 * 8) ^ ((r & 7) << 3);
            af[kg] = *reinterpret_cast<const bf16x8*>(ta + idx);
        }
#pragma unroll
        for (int nr = 0; nr < 2; ++nr)
#pragma unroll
            for (int kg = 0; kg < 4; ++kg)
                acc[mr][nr] = __builtin_amdgcn_mfma_f32_16x16x32_bf16(
                    af[kg], wf2[nr][kg], acc[mr][nr], 0, 0, 0);
    }

    float c0 = bb[colb + rr];
    float c1 = bb[colb + 16 + rr];
    float s0 = 0.f, q0 = 0.f, s1 = 0.f, q1 = 0.f;
#pragma unroll
    for (int mr = 0; mr < 4; ++mr) {
#pragma unroll
        for (int reg = 0; reg < 4; ++reg) {
            int row = row0 + mr * 16 + kg8 * 4 + reg;
            bool ok = row < N;
            float v0 = fmaxf(acc[mr][0][reg] + c0, 0.0f);
            float v1 = fmaxf(acc[mr][1][reg] + c1, 0.0f);
            if (ok) {
                hb_out[(size_t)row * 128 + colb + rr]      = f2bf(v0);
                hb_out[(size_t)row * 128 + colb + 16 + rr] = f2bf(v1);
                s0 += v0; q0 += v0 * v0;
                s1 += v1; q1 += v1 * v1;
            }
        }
    }
    s0 += __shfl_xor(s0, 16); s0 += __shfl_xor(s0, 32);
    q0 += __shfl_xor(q0, 16); q0 += __shfl_xor(q0, 32);
    s1 += __shfl_xor(s1, 16); s1 += __shfl_xor(s1, 32);
    q1 += __shfl_xor(q1, 16); q1 += __shfl_xor(q1, 32);
    if (kg8 == 0) {
        ssum[colb + rr]            = s0;
        ssum[128 + colb + rr]      = q0;
        ssum[colb + 16 + rr]       = s1;
        ssum[128 + colb + 16 + rr] = q1;
    }
    __syncthreads();
    partial[(size_t)blockIdx.x * 256 + t] = ssum[t];
}

// ---------------------------------------------------------------------------
__global__ __launch_bounds__(256) void reduce_k(const float* __restrict__ partial,
                                                float* __restrict__ stats, int nrows)
{
    int t = threadIdx.x;
    int chunk = (nrows + gridDim.x - 1) / gridDim.x;
    int lo = blockIdx.x * chunk;
    int hi = lo + chunk; if (hi > nrows) hi = nrows;
    float acc = 0.f;
    for (int r = lo; r < hi; ++r)
        acc += partial[(size_t)r * 256 + t];
    if (hi > lo) atomicAdd(&stats[t], acc);
}

// ---------------------------------------------------------------------------
__global__ __launch_bounds__(256) void bn_apply_bf_k(
    const u32* __restrict__ h2b, const float* __restrict__ stats,
    const float* __restrict__ gamma, const float* __restrict__ beta,
    float* __restrict__ out, int N)
{
    __shared__ float sc[128], sh[128];
    int t = threadIdx.x;
    if (t < 128) {
        float invN = 1.0f / (float)N;
        float mean = stats[t] * invN;
        float var  = stats[128 + t] * invN - mean * mean;
        float s = gamma[t] * rsqrtf(var + 1e-5f);
        sc[t] = s;
        sh[t] = beta[t] - mean * s;
    }
    __syncthreads();
    int total2 = N * 64;
    for (int i = blockIdx.x * 256 + t; i < total2; i += gridDim.x * 256) {
        u32 v = h2b[i];
        int c = (i & 63) * 2;
        float2 o;
        o.x = bf_lo(v) * sc[c]     + sh[c];
        o.y = bf_hi(v) * sc[c + 1] + sh[c + 1];
        reinterpret_cast<float2*>(out)[i] = o;
    }
}

// ---------------------------------------------------------------------------
extern "C" void kernel_launch(void* const* d_in, const int* in_sizes, int n_in,
                              void* d_out, int out_size, void* d_ws, size_t ws_size,
                              hipStream_t stream)
{
    const float* x   = (const float*)d_in[0];
    const int*   ei  = (const int*)d_in[1];
    const float* W1a = (const float*)d_in[2];
    const float* b1a = (const float*)d_in[3];
    const float* W1b = (const float*)d_in[4];
    const float* b1b = (const float*)d_in[5];
    const float* g1  = (const float*)d_in[6];
    const float* be1 = (const float*)d_in[7];
    const float* W2a = (const float*)d_in[8];
    const float* b2a = (const float*)d_in[9];
    const float* W2b = (const float*)d_in[10];
    const float* b2b = (const float*)d_in[11];
    const float* g2  = (const float*)d_in[12];
    const float* be2 = (const float*)d_in[13];

    const int N = in_sizes[0] / 128;
    const int E = in_sizes[1] / 2;
    const int* esrc = ei;
    const int* edst = ei + E;
    const int NB = (N + 127) >> 7;   // 128-row buckets; requires N <= 131072

    const int mblocks = (N + 63) / 64;
    const int gblocks = (N + 3) / 4;   // 1 row/wave, 4 rows/block

    // ---- workspace carve ----
    char* p = (char*)d_ws;
    const size_t featb  = (size_t)N * 128 * sizeof(u16);          // 25.6 MB
    const size_t featbz = (size_t)(N + 16) * 128 * sizeof(u16);   // +16 zero rows
    u16* xa = (u16*)p;            p += featb;               // gather output
    u16* h1 = (u16*)p;            p += featbz;              // layer out (+zeros)
    u16* xb = (u16*)p;            p += featbz;              // bf16 input (+zeros)
    u16* wf = (u16*)p;            p += 4 * 16384 * sizeof(u16);
    int* slots = (int*)p;         p += ((size_t)E + 15 * (size_t)N) * sizeof(int) + 64;
    int* deg   = (int*)p;         p += (size_t)N * sizeof(int);
    int* offs  = (int*)p;         p += (size_t)N * sizeof(int);
    int* gcount = (int*)p;        p += 1024 * sizeof(int);
    int* goffs  = (int*)p;        p += 1032 * sizeof(int);
    int* gcur   = (int*)p;        p += 1024 * sizeof(int);
    int* pbtotal = (int*)p;       p += 1024 * sizeof(int);
    int* pbase   = (int*)p;       p += 1032 * sizeof(int);
    float* stats = (float*)p;     p += 512 * sizeof(float);
    float* partial = (float*)p;   p += (size_t)mblocks * 256 * sizeof(float);
    u32* bpacked = (u32*)xa;      // alias (E*4 <= featb), dead before gather<0>

    u16* wf1a = wf;
    u16* wf1b = wf + 16384;
    u16* wf2a = wf + 32768;
    u16* wf2b = wf + 49152;
    float* stats1 = stats;
    float* stats2 = stats + 256;

    float* h = (float*)d_out;

    // ---- one-time prep ----
    hipMemsetAsync(gcount, 0, 1024 * sizeof(int), stream);
    hipMemsetAsync(xb + (size_t)N * 128, 0, 16 * 256, stream);   // zero rows
    hipMemsetAsync(h1 + (size_t)N * 128, 0, 16 * 256, stream);   // zero rows
    prep_k<<<2560, 256, 0, stream>>>(x, (u32*)xb, N * 32,
                                     edst, gcount, E, NB,
                                     W1a, W1b, W2a, W2b, wf);
    bscan_k<<<1, 1024, 0, stream>>>(gcount, goffs, gcur, NB);
    bfill_k<<<256, 256, 0, stream>>>(esrc, edst, gcur, bpacked, E, NB);
    fsortA_k<<<NB, 256, 0, stream>>>(bpacked, goffs, deg, pbtotal, N);
    bscan_k<<<1, 1024, 0, stream>>>(pbtotal, pbase, (int*)nullptr, NB);
    fsortB_k<<<NB, 256, 0, stream>>>(bpacked, goffs, pbase, deg, slots, offs, N);
    hipMemsetAsync(stats, 0, 512 * sizeof(float), stream);

    // ---- layer 1: gather -> MLP (bf16 h1 + partial) -> reduce stats1 ----
    gather_k<0><<<gblocks, 256, 0, stream>>>((const u32*)xb, offs, deg, slots,
                                             nullptr, nullptr, nullptr, (u32*)xa, N);
    mlp_mfma_k<<<mblocks, 256, 0, stream>>>(xa, wf1a, b1a, wf1b, b1b,
                                            h1, partial, N);
    reduce_k<<<32, 256, 0, stream>>>(partial, stats1, mblocks);

    // ---- layer 2: gather (BN1 folded) -> MLP (bf16 h2 -> h1 buf) -> stats2 ----
    gather_k<1><<<gblocks, 256, 0, stream>>>((const u32*)h1, offs, deg, slots,
                                             stats1, g1, be1, (u32*)xa, N);
    mlp_mfma_k<<<mblocks, 256, 0, stream>>>(xa, wf2a, b2a, wf2b, b2b,
                                            h1, partial, N);
    reduce_k<<<32, 256, 0, stream>>>(partial, stats2, mblocks);

    // ---- final BN: bf16 h2 -> f32 d_out ----
    bn_apply_bf_k<<<2048, 256, 0, stream>>>((const u32*)h1, stats2, g2, be2, h, N);
}

// Round 15
// 281.684 us; speedup vs baseline: 1.0197x; 1.0197x over previous
//
#include <hip/hip_runtime.h>
#include <hip/hip_bf16.h>

typedef unsigned int u32;
typedef unsigned short u16;
typedef short bf16x8 __attribute__((ext_vector_type(8)));
typedef float f32x4 __attribute__((ext_vector_type(4)));
typedef float f32x2 __attribute__((ext_vector_type(2)));

static __device__ __forceinline__ float bf_lo(u32 v) { return __uint_as_float(v << 16); }
static __device__ __forceinline__ float bf_hi(u32 v) { return __uint_as_float(v & 0xffff0000u); }
static __device__ __forceinline__ u16 f2bf(float f) {
    u32 u = __float_as_uint(f);
    u32 r = u + 0x7fffu + ((u >> 16) & 1u);   // RNE; inputs finite
    return (u16)(r >> 16);
}
static __device__ __forceinline__ u32 pack2(float a, float b) {
    return ((u32)f2bf(b) << 16) | (u32)f2bf(a);
}

// ---------------------------------------------------------------------------
// merged prep: blocks [0,2048) convert f32->bf16; [2048,2304) bhist;
// [2304,2560) wprep
// ---------------------------------------------------------------------------
__global__ __launch_bounds__(256) void prep_k(const float* __restrict__ x,
                                              u32* __restrict__ out2, int total4,
                                              const int* __restrict__ edst,
                                              int* __restrict__ gcount, int E, int NB,
                                              const float* __restrict__ Wa,
                                              const float* __restrict__ Wb,
                                              const float* __restrict__ Wc,
                                              const float* __restrict__ Wd,
                                              u16* __restrict__ Wf)
{
    int b = blockIdx.x, t = threadIdx.x;
    if (b < 2048) {                       // ---- convert role ----
        for (int i = b * 256 + t; i < total4; i += 2048 * 256) {
            f32x4 v = __builtin_nontemporal_load(reinterpret_cast<const f32x4*>(x) + i);
            out2[2 * i + 0] = pack2(v.x, v.y);
            out2[2 * i + 1] = pack2(v.z, v.w);
        }
    } else if (b < 2304) {                // ---- bhist role ----
        __shared__ int lh[1024];
        for (int i = t; i < 1024; i += 256) lh[i] = 0;
        __syncthreads();
        for (int e = (b - 2048) * 256 + t; e < E; e += 256 * 256)
            atomicAdd(&lh[edst[e] >> 7], 1);
        __syncthreads();
        for (int bb = t; bb < NB; bb += 256)
            if (lh[bb]) atomicAdd(&gcount[bb], lh[bb]);
    } else {                              // ---- wprep role ----
        int g = (b - 2304) * 256 + t;     // 0..65535
        int which = g >> 14;
        int tt = g & 16383;
        const float* W = which == 0 ? Wa : which == 1 ? Wb : which == 2 ? Wc : Wd;
        int j  = tt & 7;
        int l  = (tt >> 3) & 63;
        int nb = (tt >> 9) & 7;
        int kg = (tt >> 12) & 3;
        int k  = kg * 32 + (l >> 4) * 8 + j;
        int n  = nb * 16 + (l & 15);
        Wf[g] = f2bf(W[k * 128 + n]);
    }
}

__global__ __launch_bounds__(1024) void bscan_k(const int* __restrict__ gcount,
                                                int* __restrict__ goffs,
                                                int* __restrict__ gcur, int NB)
{
    __shared__ int s[1024];
    int t = threadIdx.x;
    int v = (t < NB) ? gcount[t] : 0;
    s[t] = v; __syncthreads();
    for (int d = 1; d < 1024; d <<= 1) {
        int x = (t >= d) ? s[t - d] : 0;
        __syncthreads();
        s[t] += x;
        __syncthreads();
    }
    if (t < NB) { int o = s[t] - v; goffs[t] = o; gcur[t] = o; }
    if (t == NB - 1) goffs[NB] = s[t];
}

__global__ __launch_bounds__(256) void bfill_k(const int* __restrict__ esrc,
                                               const int* __restrict__ edst,
                                               int* __restrict__ gcur,
                                               u32* __restrict__ bpacked, int E, int NB)
{
    __shared__ int lh[1024];
    __shared__ int lbase[1024];
    int t = threadIdx.x;
    for (int i = t; i < 1024; i += 256) lh[i] = 0;
    __syncthreads();
    int per = (E + gridDim.x - 1) / gridDim.x;
    int lo = blockIdx.x * per;
    int hi = lo + per; if (hi > E) hi = E;
    for (int e = lo + t; e < hi; e += 256) atomicAdd(&lh[edst[e] >> 7], 1);
    __syncthreads();
    for (int b = t; b < NB; b += 256) {
        int c = lh[b];
        lbase[b] = c ? atomicAdd(&gcur[b], c) : 0;
    }
    __syncthreads();
    for (int i = t; i < 1024; i += 256) lh[i] = 0;   // reuse as local cursor
    __syncthreads();
    for (int e = lo + t; e < hi; e += 256) {
        int d = edst[e];
        int b = d >> 7;
        int idx = atomicAdd(&lh[b], 1);
        bpacked[lbase[b] + idx] = ((u32)(d & 127) << 17) | (u32)esrc[e];
    }
}

// ---------------------------------------------------------------------------
// fine counting sort within each bucket -> dst-sorted slots + per-row offs/deg
// ---------------------------------------------------------------------------
__global__ __launch_bounds__(256) void fsort_k(const u32* __restrict__ bpacked,
                                               const int* __restrict__ goffs,
                                               int* __restrict__ slots,
                                               int* __restrict__ offs,
                                               int* __restrict__ deg, int N)
{
    __shared__ int cnt[128];
    __shared__ int roff[128];
    __shared__ int sb[128];
    int b = blockIdx.x, t = threadIdx.x;
    int start = goffs[b], end = goffs[b + 1];
    if (t < 128) cnt[t] = 0;
    __syncthreads();
    for (int e = start + t; e < end; e += 256)
        atomicAdd(&cnt[bpacked[e] >> 17], 1);
    __syncthreads();
    if (t < 128) sb[t] = cnt[t];
    __syncthreads();
    for (int d = 1; d < 128; d <<= 1) {
        int x = (t < 128 && t >= d) ? sb[t - d] : 0;
        __syncthreads();
        if (t < 128) sb[t] += x;
        __syncthreads();
    }
    if (t < 128) roff[t] = sb[t] - cnt[t];   // exclusive prefix
    __syncthreads();
    int row0 = b * 128;
    if (t < 128 && row0 + t < N) {
        offs[row0 + t] = start + roff[t];
        deg[row0 + t]  = cnt[t];
    }
    if (t < 128) cnt[t] = 0;   // reuse as cursor
    __syncthreads();
    for (int e = start + t; e < end; e += 256) {
        u32 pk = bpacked[e];
        int local = (int)(pk >> 17);
        int idx = atomicAdd(&cnt[local], 1);
        slots[start + roff[local] + idx] = (int)(pk & 0x1FFFF);
    }
}

// ---------------------------------------------------------------------------
// gather-aggregate: one wave per row, scalar-hoisted CSR state, 16-deep
// batches + single-round-trip scalar-guarded tail (round-12 structure).
// xa store is NON-TEMPORAL: don't let the 25.6MB output stream evict the
// random-read xb working set from L2 (FETCH service rate is the wall).
// MODE 0: xa[row] = bf16( x[row] + sum_nbr x[s] )
// MODE 1: prev-layer BN folded in: xa[row] = bf16( sc.(h+sum) + (deg+1).sh )
// ---------------------------------------------------------------------------
#define ROWP(s) reinterpret_cast<const u32*>(xbase + ((size_t)(u32)(s) << 8))

template<int MODE>
__global__ __launch_bounds__(256) void gather_k(const u32* __restrict__ xb2,
                                                const int* __restrict__ offs,
                                                const int* __restrict__ deg,
                                                const int* __restrict__ slots,
                                                const float* __restrict__ stats_in,
                                                const float* __restrict__ g_in,
                                                const float* __restrict__ be_in,
                                                u32* __restrict__ xa2, int N)
{
    __shared__ float sc[128], sh[128];
    int t = threadIdx.x;
    if (MODE == 1) {
        if (t < 128) {
            float invN = 1.0f / (float)N;
            float mean = stats_in[t] * invN;
            float var  = stats_in[128 + t] * invN - mean * mean;
            float s = g_in[t] * rsqrtf(var + 1e-5f);
            sc[t] = s;
            sh[t] = be_in[t] - mean * s;
        }
        __syncthreads();
    }

    int row = blockIdx.x * 4 + (t >> 6);
    if (row >= N) return;
    int lane = t & 63;
    const char* xbase = (const char*)xb2;

    u32 self = ROWP(row)[lane];
    float ax0 = bf_lo(self), ay0 = bf_hi(self);
    float ax1 = 0.f, ay1 = 0.f, ax2 = 0.f, ay2 = 0.f, ax3 = 0.f, ay3 = 0.f;

    // wave-uniform CSR state -> SGPRs
    int ustart = __builtin_amdgcn_readfirstlane(offs[row]);
    int udg    = __builtin_amdgcn_readfirstlane(deg[row]);

    int e = 0;
    for (; e + 16 <= udg; e += 16) {   // scalar slot fetch, 16 loads in flight
        int s0 = slots[ustart + e + 0],  s1 = slots[ustart + e + 1];
        int s2 = slots[ustart + e + 2],  s3 = slots[ustart + e + 3];
        int s4 = slots[ustart + e + 4],  s5 = slots[ustart + e + 5];
        int s6 = slots[ustart + e + 6],  s7 = slots[ustart + e + 7];
        int s8 = slots[ustart + e + 8],  s9 = slots[ustart + e + 9];
        int sA = slots[ustart + e + 10], sB = slots[ustart + e + 11];
        int sC = slots[ustart + e + 12], sD = slots[ustart + e + 13];
        int sE = slots[ustart + e + 14], sF = slots[ustart + e + 15];
        u32 v0 = ROWP(s0)[lane], v1 = ROWP(s1)[lane];
        u32 v2 = ROWP(s2)[lane], v3 = ROWP(s3)[lane];
        u32 v4 = ROWP(s4)[lane], v5 = ROWP(s5)[lane];
        u32 v6 = ROWP(s6)[lane], v7 = ROWP(s7)[lane];
        u32 v8 = ROWP(s8)[lane], v9 = ROWP(s9)[lane];
        u32 vA = ROWP(sA)[lane], vB = ROWP(sB)[lane];
        u32 vC = ROWP(sC)[lane], vD = ROWP(sD)[lane];
        u32 vE = ROWP(sE)[lane], vF = ROWP(sF)[lane];
        ax0 += bf_lo(v0); ay0 += bf_hi(v0);  ax1 += bf_lo(v1); ay1 += bf_hi(v1);
        ax2 += bf_lo(v2); ay2 += bf_hi(v2);  ax3 += bf_lo(v3); ay3 += bf_hi(v3);
        ax0 += bf_lo(v4); ay0 += bf_hi(v4);  ax1 += bf_lo(v5); ay1 += bf_hi(v5);
        ax2 += bf_lo(v6); ay2 += bf_hi(v6);  ax3 += bf_lo(v7); ay3 += bf_hi(v7);
        ax0 += bf_lo(v8); ay0 += bf_hi(v8);  ax1 += bf_lo(v9); ay1 += bf_hi(v9);
        ax2 += bf_lo(vA); ay2 += bf_hi(vA);  ax3 += bf_lo(vB); ay3 += bf_hi(vB);
        ax0 += bf_lo(vC); ay0 += bf_hi(vC);  ax1 += bf_lo(vD); ay1 += bf_hi(vD);
        ax2 += bf_lo(vE); ay2 += bf_hi(vE);  ax3 += bf_lo(vF); ay3 += bf_hi(vF);
    }
    int k = udg - e;                   // 0..15, wave-uniform
    if (k) {
        // slot reads may overrun this row (into next row's slots / 64B pad):
        // values masked below, so harmless. All loads grouped -> 1 round trip.
        int s0 = slots[ustart + e + 0],  s1 = slots[ustart + e + 1];
        int s2 = slots[ustart + e + 2],  s3 = slots[ustart + e + 3];
        int s4 = slots[ustart + e + 4],  s5 = slots[ustart + e + 5];
        int s6 = slots[ustart + e + 6],  s7 = slots[ustart + e + 7];
        int s8 = slots[ustart + e + 8],  s9 = slots[ustart + e + 9];
        int sA = slots[ustart + e + 10], sB = slots[ustart + e + 11];
        int sC = slots[ustart + e + 12], sD = slots[ustart + e + 13];
        int sE = slots[ustart + e + 14];
        u32 v0 = 0, v1 = 0, v2 = 0, v3 = 0, v4 = 0, v5 = 0, v6 = 0, v7 = 0;
        u32 v8 = 0, v9 = 0, vA = 0, vB = 0, vC = 0, vD = 0, vE = 0;
        v0 = ROWP(s0)[lane];                       // k >= 1
        if (k > 1)  v1 = ROWP(s1)[lane];
        if (k > 2)  v2 = ROWP(s2)[lane];
        if (k > 3)  v3 = ROWP(s3)[lane];
        if (k > 4)  v4 = ROWP(s4)[lane];
        if (k > 5)  v5 = ROWP(s5)[lane];
        if (k > 6)  v6 = ROWP(s6)[lane];
        if (k > 7)  v7 = ROWP(s7)[lane];
        if (k > 8)  v8 = ROWP(s8)[lane];
        if (k > 9)  v9 = ROWP(s9)[lane];
        if (k > 10) vA = ROWP(sA)[lane];
        if (k > 11) vB = ROWP(sB)[lane];
        if (k > 12) vC = ROWP(sC)[lane];
        if (k > 13) vD = ROWP(sD)[lane];
        if (k > 14) vE = ROWP(sE)[lane];
        // bf(0) == 0.0f -> unconditional accumulate
        ax0 += bf_lo(v0); ay0 += bf_hi(v0);  ax1 += bf_lo(v1); ay1 += bf_hi(v1);
        ax2 += bf_lo(v2); ay2 += bf_hi(v2);  ax3 += bf_lo(v3); ay3 += bf_hi(v3);
        ax0 += bf_lo(v4); ay0 += bf_hi(v4);  ax1 += bf_lo(v5); ay1 += bf_hi(v5);
        ax2 += bf_lo(v6); ay2 += bf_hi(v6);  ax3 += bf_lo(v7); ay3 += bf_hi(v7);
        ax0 += bf_lo(v8); ay0 += bf_hi(v8);  ax1 += bf_lo(v9); ay1 += bf_hi(v9);
        ax2 += bf_lo(vA); ay2 += bf_hi(vA);  ax3 += bf_lo(vB); ay3 += bf_hi(vB);
        ax0 += bf_lo(vC); ay0 += bf_hi(vC);  ax1 += bf_lo(vD); ay1 += bf_hi(vD);
        ax2 += bf_lo(vE); ay2 += bf_hi(vE);
    }

    float ax = (ax0 + ax1) + (ax2 + ax3);
    float ay = (ay0 + ay1) + (ay2 + ay3);
    if (MODE == 1) {
        float d1 = (float)(udg + 1);
        ax = sc[2 * lane]     * ax + d1 * sh[2 * lane];
        ay = sc[2 * lane + 1] * ay + d1 * sh[2 * lane + 1];
    }
    __builtin_nontemporal_store(pack2(ax, ay), xa2 + (size_t)row * 64 + lane);
}

// ---------------------------------------------------------------------------
// fused MFMA MLP: h = relu(relu(XA@Wa + ba)@Wb + bb) -> bf16 out + partials.
// xa tile loads NON-TEMPORAL (read-once stream; keep h/xb resident in L2).
// W2 fragment loads issued before the relu->ta write phase.
// ---------------------------------------------------------------------------
__global__ __launch_bounds__(256) void mlp_mfma_k(
    const u16* __restrict__ xa,
    const u16* __restrict__ wfa, const float* __restrict__ ba,
    const u16* __restrict__ wfb, const float* __restrict__ bb,
    u16* __restrict__ hb_out, float* __restrict__ partial, int N)
{
    __shared__ short ta[64 * 128];   // 16 KB tile (bf16, swizzled), reused
    __shared__ float ssum[256];

    int t = threadIdx.x;
    int w = t >> 6, l = t & 63;
    int row0 = blockIdx.x * 64;

    // stage XA tile (swizzled), nt loads
    for (int c = t; c < 1024; c += 256) {
        int r = c >> 4, ci = c & 15;
        int dst = (r * 128 + ci * 8) ^ ((r & 7) << 3);
        f32x4 v;
        if (row0 + r < N)
            v = __builtin_nontemporal_load(
                reinterpret_cast<const f32x4*>(xa + ((size_t)(row0 + r) * 128 + ci * 8)));
        else
            v = f32x4{0.f, 0.f, 0.f, 0.f};
        *reinterpret_cast<f32x4*>(ta + dst) = v;
    }

    // W1 fragments
    bf16x8 wf[2][4];
#pragma unroll
    for (int nr = 0; nr < 2; ++nr) {
        int nb = 2 * w + nr;
#pragma unroll
        for (int kg = 0; kg < 4; ++kg)
            wf[nr][kg] = *reinterpret_cast<const bf16x8*>(
                wfa + ((size_t)((kg * 8 + nb) * 64 + l)) * 8);
    }
    __syncthreads();

    int rr = l & 15;
    int kg8 = l >> 4;

    f32x4 acc[4][2];
#pragma unroll
    for (int mr = 0; mr < 4; ++mr)
#pragma unroll
        for (int nr = 0; nr < 2; ++nr)
            acc[mr][nr] = f32x4{0.f, 0.f, 0.f, 0.f};

#pragma unroll
    for (int mr = 0; mr < 4; ++mr) {
        int r = mr * 16 + rr;
        bf16x8 af[4];
#pragma unroll
        for (int kg = 0; kg < 4; ++kg) {
            int idx = (r * 128 + kg * 32 + kg8 * 8) ^ ((r & 7) << 3);
            af[kg] = *reinterpret_cast<const bf16x8*>(ta + idx);
        }
#pragma unroll
        for (int nr = 0; nr < 2; ++nr)
#pragma unroll
            for (int kg = 0; kg < 4; ++kg)
                acc[mr][nr] = __builtin_amdgcn_mfma_f32_16x16x32_bf16(
                    af[kg], wf[nr][kg], acc[mr][nr], 0, 0, 0);
    }
    __syncthreads();   // all GEMM1 reads of ta complete

    // W2 fragments (independent of ta -> issue before the relu-write phase)
    bf16x8 wf2[2][4];
#pragma unroll
    for (int nr = 0; nr < 2; ++nr) {
        int nb = 2 * w + nr;
#pragma unroll
        for (int kg = 0; kg < 4; ++kg)
            wf2[nr][kg] = *reinterpret_cast<const bf16x8*>(
                wfb + ((size_t)((kg * 8 + nb) * 64 + l)) * 8);
    }

    // bias + relu -> back into ta
    int colb = w * 32;
    float b0 = ba[colb + rr];
    float b1 = ba[colb + 16 + rr];
#pragma unroll
    for (int mr = 0; mr < 4; ++mr)
#pragma unroll
        for (int nr = 0; nr < 2; ++nr) {
            float bb_ = nr ? b1 : b0;
            int col = colb + nr * 16 + rr;
#pragma unroll
            for (int reg = 0; reg < 4; ++reg) {
                int row = mr * 16 + kg8 * 4 + reg;
                float v = fmaxf(acc[mr][nr][reg] + bb_, 0.0f);
                ta[(row * 128 + col) ^ ((row & 7) << 3)] = (short)f2bf(v);
            }
        }
    __syncthreads();

#pragma unroll
    for (int mr = 0; mr < 4; ++mr)
#pragma unroll
        for (int nr = 0; nr < 2; ++nr)
            acc[mr][nr] = f32x4{0.f, 0.f, 0.f, 0.f};

#pragma unroll
    for (int mr = 0; mr < 4; ++mr) {
        int r = mr * 16 + rr;
        bf16x8 af[4];
#pragma unroll
        for (int kg = 0; kg < 4; ++kg) {
            int idx = (r * 128 + kg * 32 + kg8 * 8) ^ ((r & 7) << 3);
            af[kg] = *reinterpret_cast<const bf16x8*>(ta + idx);
        }
#pragma unroll
        for (int nr = 0; nr < 2; ++nr)
#pragma unroll
            for (int kg = 0; kg < 4; ++kg)
                acc[mr][nr] = __builtin_amdgcn_mfma_f32_16x16x32_bf16(
                    af[kg], wf2[nr][kg], acc[mr][nr], 0, 0, 0);
    }

    // bias + relu + bf16 store + per-block BN stat partial
    float c0 = bb[colb + rr];
    float c1 = bb[colb + 16 + rr];
    float s0 = 0.f, q0 = 0.f, s1 = 0.f, q1 = 0.f;
#pragma unroll
    for (int mr = 0; mr < 4; ++mr) {
#pragma unroll
        for (int reg = 0; reg < 4; ++reg) {
            int row = row0 + mr * 16 + kg8 * 4 + reg;
            bool ok = row < N;
            float v0 = fmaxf(acc[mr][0][reg] + c0, 0.0f);
            float v1 = fmaxf(acc[mr][1][reg] + c1, 0.0f);
            if (ok) {
                hb_out[(size_t)row * 128 + colb + rr]      = f2bf(v0);
                hb_out[(size_t)row * 128 + colb + 16 + rr] = f2bf(v1);
                s0 += v0; q0 += v0 * v0;
                s1 += v1; q1 += v1 * v1;
            }
        }
    }
    s0 += __shfl_xor(s0, 16); s0 += __shfl_xor(s0, 32);
    q0 += __shfl_xor(q0, 16); q0 += __shfl_xor(q0, 32);
    s1 += __shfl_xor(s1, 16); s1 += __shfl_xor(s1, 32);
    q1 += __shfl_xor(q1, 16); q1 += __shfl_xor(q1, 32);
    if (kg8 == 0) {
        ssum[colb + rr]            = s0;
        ssum[128 + colb + rr]      = q0;
        ssum[colb + 16 + rr]       = s1;
        ssum[128 + colb + 16 + rr] = q1;
    }
    __syncthreads();
    partial[(size_t)blockIdx.x * 256 + t] = ssum[t];   // coalesced, no atomics
}

// ---------------------------------------------------------------------------
// reduce partials (nrows x 256) -> stats[256]
// ---------------------------------------------------------------------------
__global__ __launch_bounds__(256) void reduce_k(const float* __restrict__ partial,
                                                float* __restrict__ stats, int nrows)
{
    int t = threadIdx.x;
    int chunk = (nrows + gridDim.x - 1) / gridDim.x;
    int lo = blockIdx.x * chunk;
    int hi = lo + chunk; if (hi > nrows) hi = nrows;
    float acc = 0.f;
    for (int r = lo; r < hi; ++r)
        acc += __builtin_nontemporal_load(partial + (size_t)r * 256 + t);
    if (hi > lo) atomicAdd(&stats[t], acc);
}

// ---------------------------------------------------------------------------
// final BN: read bf16 h2 (nt), write f32 d_out (nt; never re-read)
// ---------------------------------------------------------------------------
__global__ __launch_bounds__(256) void bn_apply_bf_k(
    const u32* __restrict__ h2b, const float* __restrict__ stats,
    const float* __restrict__ gamma, const float* __restrict__ beta,
    float* __restrict__ out, int N)
{
    __shared__ float sc[128], sh[128];
    int t = threadIdx.x;
    if (t < 128) {
        float invN = 1.0f / (float)N;
        float mean = stats[t] * invN;
        float var  = stats[128 + t] * invN - mean * mean;
        float s = gamma[t] * rsqrtf(var + 1e-5f);
        sc[t] = s;
        sh[t] = beta[t] - mean * s;
    }
    __syncthreads();
    int total2 = N * 64;   // u32 count
    for (int i = blockIdx.x * 256 + t; i < total2; i += gridDim.x * 256) {
        u32 v = __builtin_nontemporal_load(h2b + i);
        int c = (i & 63) * 2;
        f32x2 o;
        o.x = bf_lo(v) * sc[c]     + sh[c];
        o.y = bf_hi(v) * sc[c + 1] + sh[c + 1];
        __builtin_nontemporal_store(o, reinterpret_cast<f32x2*>(out) + i);
    }
}

// ---------------------------------------------------------------------------
extern "C" void kernel_launch(void* const* d_in, const int* in_sizes, int n_in,
                              void* d_out, int out_size, void* d_ws, size_t ws_size,
                              hipStream_t stream)
{
    const float* x   = (const float*)d_in[0];
    const int*   ei  = (const int*)d_in[1];
    const float* W1a = (const float*)d_in[2];
    const float* b1a = (const float*)d_in[3];
    const float* W1b = (const float*)d_in[4];
    const float* b1b = (const float*)d_in[5];
    const float* g1  = (const float*)d_in[6];
    const float* be1 = (const float*)d_in[7];
    const float* W2a = (const float*)d_in[8];
    const float* b2a = (const float*)d_in[9];
    const float* W2b = (const float*)d_in[10];
    const float* b2b = (const float*)d_in[11];
    const float* g2  = (const float*)d_in[12];
    const float* be2 = (const float*)d_in[13];

    const int N = in_sizes[0] / 128;
    const int E = in_sizes[1] / 2;
    const int* esrc = ei;
    const int* edst = ei + E;
    const int NB = (N + 127) >> 7;   // 128-row buckets; requires N <= 131072

    const int mblocks = (N + 63) / 64;
    const int gblocks = (N + 3) / 4;   // 1 row/wave, 4 rows/block

    // ---- workspace carve ----
    char* p = (char*)d_ws;
    const size_t featb = (size_t)N * 128 * sizeof(u16);     // 25.6 MB
    u16* xa = (u16*)p;            p += featb;               // gather output
    u16* h1 = (u16*)p;            p += featb;               // layer-1/2 bf16 output
    u16* xb = (u16*)p;            p += featb;               // bf16 input features
    u16* wf = (u16*)p;            p += 4 * 16384 * sizeof(u16);
    int* slots = (int*)p;         p += (size_t)E * sizeof(int) + 64;  // +64B tail overread pad
    int* deg   = (int*)p;         p += (size_t)N * sizeof(int);
    int* offs  = (int*)p;         p += (size_t)N * sizeof(int);
    int* gcount = (int*)p;        p += 1024 * sizeof(int);
    int* goffs  = (int*)p;        p += 1032 * sizeof(int);
    int* gcur   = (int*)p;        p += 1024 * sizeof(int);
    float* stats = (float*)p;     p += 512 * sizeof(float);
    float* partial = (float*)p;   p += (size_t)mblocks * 256 * sizeof(float);
    u32* bpacked = (u32*)xa;      // alias (E*4 = 6.4MB <= featb), dead early

    u16* wf1a = wf;
    u16* wf1b = wf + 16384;
    u16* wf2a = wf + 32768;
    u16* wf2b = wf + 49152;
    float* stats1 = stats;
    float* stats2 = stats + 256;

    float* h = (float*)d_out;

    // ---- one-time prep: merged convert/bhist/wprep -> scan -> fill -> sort --
    hipMemsetAsync(gcount, 0, 1024 * sizeof(int), stream);
    prep_k<<<2560, 256, 0, stream>>>(x, (u32*)xb, N * 32,
                                     edst, gcount, E, NB,
                                     W1a, W1b, W2a, W2b, wf);
    bscan_k<<<1, 1024, 0, stream>>>(gcount, goffs, gcur, NB);
    bfill_k<<<256, 256, 0, stream>>>(esrc, edst, gcur, bpacked, E, NB);
    fsort_k<<<NB, 256, 0, stream>>>(bpacked, goffs, slots, offs, deg, N);
    hipMemsetAsync(stats, 0, 512 * sizeof(float), stream);

    // ---- layer 1: gather -> MLP (bf16 h1 + partial) -> reduce stats1 ----
    gather_k<0><<<gblocks, 256, 0, stream>>>((const u32*)xb, offs, deg, slots,
                                             nullptr, nullptr, nullptr, (u32*)xa, N);
    mlp_mfma_k<<<mblocks, 256, 0, stream>>>(xa, wf1a, b1a, wf1b, b1b,
                                            h1, partial, N);
    reduce_k<<<32, 256, 0, stream>>>(partial, stats1, mblocks);

    // ---- layer 2: gather (BN1 folded) -> MLP (bf16 h2 -> h1 buf) -> stats2 ----
    gather_k<1><<<gblocks, 256, 0, stream>>>((const u32*)h1, offs, deg, slots,
                                             stats1, g1, be1, (u32*)xa, N);
    mlp_mfma_k<<<mblocks, 256, 0, stream>>>(xa, wf2a, b2a, wf2b, b2b,
                                            h1, partial, N);
    reduce_k<<<32, 256, 0, stream>>>(partial, stats2, mblocks);

    // ---- final BN: bf16 h2 -> f32 d_out ----
    bn_apply_bf_k<<<2048, 256, 0, stream>>>((const u32*)h1, stats2, g2, be2, h, N);
}